// Round 8
// baseline (492.504 us; speedup 1.0000x reference)
//
#include <hip/hip_runtime.h>

typedef unsigned short u16;
typedef __bf16 bf16x8 __attribute__((ext_vector_type(8)));
typedef float f32x4 __attribute__((ext_vector_type(4)));

__device__ __forceinline__ u16 f2bf(float f) {
  unsigned u = __builtin_bit_cast(unsigned, f);
  u += 0x7FFFu + ((u >> 16) & 1u);
  return (u16)(u >> 16);
}

#define GLOAD16(g, l) __builtin_amdgcn_global_load_lds( \
    (const __attribute__((address_space(1))) unsigned int*)(const void*)(g), \
    (__attribute__((address_space(3))) unsigned int*)(void*)(l), 16, 0, 0)

// swizzled u16 index of 16B-chunk c (0..7) in row r of a 64-u16-wide LDS tile
#define SW(r, c) (((r) << 6) + ((((c) ^ ((r) & 7))) << 3))

// ---------------------------------------------------------------- transpose + f32->bf16
__global__ __launch_bounds__(256) void tconv(const float* __restrict__ W,
                                             u16* __restrict__ Wt, int K, int N) {
  __shared__ float t[32][33];
  int n0 = blockIdx.x * 32, k0 = blockIdx.y * 32;
  int tx = threadIdx.x, ty = threadIdx.y;
#pragma unroll
  for (int j = 0; j < 4; ++j)
    t[ty + j * 8][tx] = W[(size_t)(k0 + ty + j * 8) * N + n0 + tx];
  __syncthreads();
#pragma unroll
  for (int j = 0; j < 4; ++j)
    Wt[(size_t)(n0 + ty + j * 8) * K + k0 + tx] = f2bf(t[tx][ty + j * 8]);
}

// ---------------------------------------------------------------- posenc + layernorm
template <bool PE>
__global__ __launch_bounds__(256) void ln_row(const float* __restrict__ in,
                                              const float* __restrict__ g,
                                              const float* __restrict__ be,
                                              float* __restrict__ xout,
                                              u16* __restrict__ hout) {
  const int row = blockIdx.x;
  const int tid = threadIdx.x;
  const int s = row & 2047;
  float4 xv = *(const float4*)&in[(size_t)row * 1024 + tid * 4];
  float vals[4];
  const float* xp = (const float*)&xv;
#pragma unroll
  for (int j = 0; j < 4; ++j) {
    float v = xp[j];
    if (PE) {
      int d = tid * 4 + j;
      float freq = powf(10000.f, -2.f * (float)d * (1.f / 1024.f));
      float ang = (float)s * freq;
      v += (d & 1) ? cosf(ang) : sinf(ang);
    }
    vals[j] = v;
  }
  if (PE) {
    float4 st;
    float* sp = (float*)&st;
#pragma unroll
    for (int j = 0; j < 4; ++j) sp[j] = vals[j];
    *(float4*)&xout[(size_t)row * 1024 + tid * 4] = st;
  }
  float sum = vals[0] + vals[1] + vals[2] + vals[3];
  float sq = vals[0] * vals[0] + vals[1] * vals[1] + vals[2] * vals[2] + vals[3] * vals[3];
#pragma unroll
  for (int d = 1; d < 64; d <<= 1) {
    sum += __shfl_xor(sum, d);
    sq += __shfl_xor(sq, d);
  }
  __shared__ float red[8];
  int wave = tid >> 6, lane = tid & 63;
  if (lane == 0) { red[wave] = sum; red[4 + wave] = sq; }
  __syncthreads();
  sum = red[0] + red[1] + red[2] + red[3];
  sq = red[4] + red[5] + red[6] + red[7];
  float mu = sum * (1.f / 1024.f);
  float var = sq * (1.f / 1024.f) - mu * mu;
  float rv = rsqrtf(var + 1e-5f);
#pragma unroll
  for (int j = 0; j < 4; ++j) {
    int d = tid * 4 + j;
    hout[(size_t)row * 1024 + d] = f2bf((vals[j] - mu) * rv * g[d] + be[d]);
  }
}

// ---------------------------------------------------------------- GEMM: 8-phase schedule
// C = A @ Bt^T.  Tile 256x256, BK=64 (2 kk-halves of 32), 512 thr = 8 waves (2M x 4N).
// Per-wave out 128x64 = acc[8][4].  LDS 128KB: [2 dbuf][2 kk][128 lds-rows][64] for A and B,
// two global rows packed per LDS row; 8-chunk XOR swizzle (conflict-free, gload-linear).
// Phase: {ds_read frags || stage 1 half (2 gloads) -> barrier -> lgkm(0) -> setprio+16 MFMA
// -> [vmcnt(4) at phases 4/8] -> barrier}.  Loads never drain to 0 in-loop (T3+T4).
#define EPI_QKV 0
#define EPI_OPROJ 1
#define EPI_FFN1 2
#define EPI_FFN2 3

template <int EPI>
__global__ __launch_bounds__(512, 1) void gemm8p(
    const u16* __restrict__ A, const u16* __restrict__ Bt, int K, int ntx,
    const float* __restrict__ bias, const float* __restrict__ resid,
    float* __restrict__ outf, u16* __restrict__ outb,
    u16* __restrict__ oq, u16* __restrict__ okk, u16* __restrict__ ovt) {
  __shared__ __align__(16) u16 Als[2][2][8192];
  __shared__ __align__(16) u16 Bls[2][2][8192];
  const int tid = threadIdx.x;
  const int wave = tid >> 6, lane = tid & 63;
  const int wm = wave >> 2, wn = wave & 3;
  const int lrow = lane & 15, lhi = lane >> 4;
  const int nwg = gridDim.x;
  const int wid = ((int)blockIdx.x & 7) * (nwg >> 3) + ((int)blockIdx.x >> 3);
  const int m0 = (wid / ntx) * 256, n0 = (wid % ntx) * 256;
  const int NT = K >> 6, NIT = NT >> 1;

  // staging geometry: lds row j = g*64 + wave*8 + (lane>>3); slot = lane&7 holds
  // global (row 2j + (u>>2), col-chunk (u&3)) with u = (lane&7)^(j&7)  [involution]
  const int u = (lane & 7) ^ ((lane >> 3) & 7);
  const int srow2 = wave * 8 + (lane >> 3);
  const size_t aR0 = (size_t)(m0 + 2 * srow2 + (u >> 2)) * K + (u & 3) * 8;
  const size_t aR1 = aR0 + (size_t)128 * K;
  const size_t bR0 = (size_t)(n0 + 2 * srow2 + (u >> 2)) * K + (u & 3) * 8;
  const size_t bR1 = bR0 + (size_t)128 * K;
  // fragment read: global row r -> lds row j=r>>1, slot ((r&1)*4+lhi)^(j&7)
  const int jchk = ((lrow >> 1) << 6) + (((((lrow & 1) << 2) + lhi) ^ ((lrow >> 1) & 7)) << 3);

#define STG_A(b, kk, kof) do { \
    GLOAD16(A + aR0 + (kof) + (kk) * 32, &Als[b][kk][wave * 512]); \
    GLOAD16(A + aR1 + (kof) + (kk) * 32, &Als[b][kk][4096 + wave * 512]); \
  } while (0)
#define STG_B(b, kk, kof) do { \
    GLOAD16(Bt + bR0 + (kof) + (kk) * 32, &Bls[b][kk][wave * 512]); \
    GLOAD16(Bt + bR1 + (kof) + (kk) * 32, &Bls[b][kk][4096 + wave * 512]); \
  } while (0)
#define VM4 asm volatile("s_waitcnt vmcnt(4)" ::: "memory")

  f32x4 acc[8][4] = {};
  bf16x8 afr[4], bfr[4];

#define PHASE(TB, KK, MH, READB, STGSTMT, ENDVM) do { \
    if (READB) { \
      _Pragma("unroll") \
      for (int nf = 0; nf < 4; ++nf) \
        bfr[nf] = *(const bf16x8*)&Bls[TB][KK][wn * 2048 + nf * 512 + jchk]; \
    } \
    _Pragma("unroll") \
    for (int a = 0; a < 4; ++a) \
      afr[a] = *(const bf16x8*)&Als[TB][KK][wm * 4096 + ((MH) * 4 + a) * 512 + jchk]; \
    STGSTMT; \
    __builtin_amdgcn_sched_barrier(0); \
    __builtin_amdgcn_s_barrier(); \
    asm volatile("s_waitcnt lgkmcnt(0)" ::: "memory"); \
    __builtin_amdgcn_sched_barrier(0); \
    __builtin_amdgcn_s_setprio(1); \
    _Pragma("unroll") \
    for (int a = 0; a < 4; ++a) \
      _Pragma("unroll") \
      for (int nf = 0; nf < 4; ++nf) \
        acc[(MH) * 4 + a][nf] = \
            __builtin_amdgcn_mfma_f32_16x16x32_bf16(afr[a], bfr[nf], acc[(MH) * 4 + a][nf], 0, 0, 0); \
    __builtin_amdgcn_s_setprio(0); \
    __builtin_amdgcn_sched_barrier(0); \
    ENDVM; \
    __builtin_amdgcn_s_barrier(); \
    asm volatile("" ::: "memory"); \
    __builtin_amdgcn_sched_barrier(0); \
  } while (0)

  // prologue: tile0 (both kk) + tile1 kk0; vmcnt(4) leaves tile1-kk0 in flight
  STG_A(0, 0, 0); STG_B(0, 0, 0);
  STG_A(0, 1, 0); STG_B(0, 1, 0);
  STG_A(1, 0, 64); STG_B(1, 0, 64);
  VM4;
  __builtin_amdgcn_s_barrier();
  asm volatile("" ::: "memory");

  for (int it = 0; it < NIT; ++it) {
    const int kof1 = (2 * it + 1) << 6;
    const int t2 = 2 * it + 2, t3 = 2 * it + 3;
    const int kof2 = (t2 < NT) ? (t2 << 6) : 0;
    const int kof3 = (t3 < NT) ? (t3 << 6) : 0;
    PHASE(0, 0, 0, 1, STG_A(1, 1, kof1), );
    PHASE(0, 0, 1, 0, STG_B(1, 1, kof1), );
    PHASE(0, 1, 0, 1, STG_A(0, 0, kof2), );
    PHASE(0, 1, 1, 0, STG_B(0, 0, kof2), VM4);
    PHASE(1, 0, 0, 1, STG_A(0, 1, kof2), );
    PHASE(1, 0, 1, 0, STG_B(0, 1, kof2), );
    PHASE(1, 1, 0, 1, STG_A(1, 0, kof3), );
    PHASE(1, 1, 1, 0, STG_B(1, 0, kof3), VM4);
  }
  asm volatile("s_waitcnt vmcnt(0)" ::: "memory");

#pragma unroll
  for (int mf = 0; mf < 8; ++mf) {
#pragma unroll
    for (int nf = 0; nf < 4; ++nf) {
#pragma unroll
      for (int i = 0; i < 4; ++i) {
        int row = m0 + wm * 128 + mf * 16 + lhi * 4 + i;
        int col = n0 + wn * 64 + nf * 16 + lrow;
        float v = acc[mf][nf][i];
        if (EPI == EPI_QKV) {
          int which = col >> 10, c = col & 1023;
          int h = c >> 6, hd = c & 63;
          int b = row >> 11, s = row & 2047;
          size_t qk = (((size_t)(b * 16 + h) * 2048 + s) << 6) + hd;
          if (which == 0) oq[qk] = f2bf(v * 0.03125f);
          else if (which == 1) okk[qk] = f2bf(v);
          else ovt[((size_t)(b * 16 + h) * 64 + hd) * 2048 + s] = f2bf(v);
        } else if (EPI == EPI_OPROJ) {
          size_t idx = (size_t)row * 1024 + col;
          outf[idx] = v + resid[idx];
        } else if (EPI == EPI_FFN1) {
          float t = v + bias[col];
          t = t > 0.f ? t : 0.01f * t;
          outb[(size_t)row * 3072 + col] = f2bf(t);
        } else {  // FFN2
          size_t idx = (size_t)row * 1024 + col;
          outf[idx] = v + bias[col] + resid[idx];
        }
      }
    }
  }
#undef PHASE
#undef STG_A
#undef STG_B
#undef VM4
}

// ---------------------------------------------------------------- flash attention (R6, unchanged)
__global__ __launch_bounds__(256, 3) void attn_fwd(const u16* __restrict__ qb,
                                                   const u16* __restrict__ kbuf,
                                                   const u16* __restrict__ vtb,
                                                   u16* __restrict__ ob) {
  __shared__ __align__(16) u16 Kl[2][64 * 64];
  __shared__ __align__(16) u16 Vl[2][64 * 64];
  __shared__ __align__(16) u16 Pl[128 * 64];
  const int tid = threadIdx.x, wave = tid >> 6, lane = tid & 63;
  const int wid = (blockIdx.x & 7) * 128 + (blockIdx.x >> 3);
  const int bh = wid >> 4, qt = wid & 15;
  const int lrow = lane & 15, lhi = lane >> 4;
  const u16* Qg = qb + (((size_t)bh * 2048 + qt * 128) << 6);
  const u16* Kg = kbuf + ((size_t)bh * 2048 << 6);
  const u16* Vg = vtb + (size_t)bh * 64 * 2048;
  const int srow = tid >> 3;
  const int swsrc = ((tid & 7) ^ (srow & 7)) * 8;

#pragma unroll
  for (int j = 0; j < 4; ++j)
    GLOAD16(Qg + (size_t)(srow + j * 32) * 64 + swsrc, &Pl[j * 2048 + wave * 512]);
#pragma unroll
  for (int j = 0; j < 2; ++j) {
    int r = srow + j * 32;
    GLOAD16(Kg + (size_t)r * 64 + swsrc, &Kl[0][j * 2048 + wave * 512]);
    GLOAD16(Vg + (size_t)r * 2048 + swsrc, &Vl[0][j * 2048 + wave * 512]);
  }
  __syncthreads();

  bf16x8 qf[2][2];
#pragma unroll
  for (int m = 0; m < 2; ++m)
#pragma unroll
    for (int kk = 0; kk < 2; ++kk)
      qf[m][kk] = *(const bf16x8*)&Pl[SW(wave * 32 + m * 16 + lrow, kk * 4 + lhi)];

  f32x4 oacc[2][4] = {};
  float lsum[8];
#pragma unroll
  for (int i = 0; i < 8; ++i) lsum[i] = 0.f;

  int cur = 0;
  for (int kv = 0; kv < 2048; kv += 64) {
    if (kv) __syncthreads();
    if (kv + 64 < 2048) {
#pragma unroll
      for (int j = 0; j < 2; ++j) {
        int r = srow + j * 32;
        GLOAD16(Kg + (size_t)(kv + 64 + r) * 64 + swsrc, &Kl[cur ^ 1][j * 2048 + wave * 512]);
        GLOAD16(Vg + (size_t)r * 2048 + kv + 64 + swsrc, &Vl[cur ^ 1][j * 2048 + wave * 512]);
      }
    }

    f32x4 sf[2][4] = {};
#pragma unroll
    for (int n = 0; n < 4; ++n) {
#pragma unroll
      for (int kk = 0; kk < 2; ++kk) {
        bf16x8 kf = *(const bf16x8*)&Kl[cur][SW(n * 16 + lrow, kk * 4 + lhi)];
        sf[0][n] = __builtin_amdgcn_mfma_f32_16x16x32_bf16(qf[0][kk], kf, sf[0][n], 0, 0, 0);
        sf[1][n] = __builtin_amdgcn_mfma_f32_16x16x32_bf16(qf[1][kk], kf, sf[1][n], 0, 0, 0);
      }
    }
#pragma unroll
    for (int m = 0; m < 2; ++m) {
#pragma unroll
      for (int i = 0; i < 4; ++i) {
        float rs = 0.f;
#pragma unroll
        for (int n = 0; n < 4; ++n) {
          float p = __expf(sf[m][n][i]);
          sf[m][n][i] = p;
          rs += p;
        }
        lsum[m * 4 + i] += rs;
      }
    }
#pragma unroll
    for (int m = 0; m < 2; ++m)
#pragma unroll
      for (int n = 0; n < 4; ++n)
#pragma unroll
        for (int i = 0; i < 4; ++i) {
          int pr = wave * 32 + m * 16 + lhi * 4 + i;
          Pl[SW(pr, n * 2 + (lrow >> 3)) + (lrow & 7)] = f2bf(sf[m][n][i]);
        }
#pragma unroll
    for (int kk = 0; kk < 2; ++kk) {
      bf16x8 pf0 = *(const bf16x8*)&Pl[SW(wave * 32 + 0 + lrow, kk * 4 + lhi)];
      bf16x8 pf1 = *(const bf16x8*)&Pl[SW(wave * 32 + 16 + lrow, kk * 4 + lhi)];
#pragma unroll
      for (int n = 0; n < 4; ++n) {
        bf16x8 vf = *(const bf16x8*)&Vl[cur][SW(n * 16 + lrow, kk * 4 + lhi)];
        oacc[0][n] = __builtin_amdgcn_mfma_f32_16x16x32_bf16(pf0, vf, oacc[0][n], 0, 0, 0);
        oacc[1][n] = __builtin_amdgcn_mfma_f32_16x16x32_bf16(pf1, vf, oacc[1][n], 0, 0, 0);
      }
    }
    cur ^= 1;
  }

#pragma unroll
  for (int idx = 0; idx < 8; ++idx)
#pragma unroll
    for (int d = 1; d < 16; d <<= 1)
      lsum[idx] += __shfl_xor(lsum[idx], d, 16);

  const int b = bh >> 4, h = bh & 15;
#pragma unroll
  for (int m = 0; m < 2; ++m)
#pragma unroll
    for (int i = 0; i < 4; ++i) {
      int qrow = qt * 128 + wave * 32 + m * 16 + lhi * 4 + i;
      float inv = 1.f / lsum[m * 4 + i];
#pragma unroll
      for (int n = 0; n < 4; ++n) {
        int hd = n * 16 + lrow;
        ob[((size_t)(b * 2048 + qrow)) * 1024 + h * 64 + hd] = f2bf(oacc[m][n][i] * inv);
      }
    }
}

// ---------------------------------------------------------------- launch
extern "C" void kernel_launch(void* const* d_in, const int* in_sizes, int n_in,
                              void* d_out, int out_size, void* d_ws, size_t ws_size,
                              hipStream_t stream) {
  const float* x = (const float*)d_in[0];
  const float* Wq = (const float*)d_in[1];
  const float* Wk = (const float*)d_in[2];
  const float* Wv = (const float*)d_in[3];
  const float* Wo = (const float*)d_in[4];
  const float* W1 = (const float*)d_in[5];
  const float* b1 = (const float*)d_in[6];
  const float* W2 = (const float*)d_in[7];
  const float* b2 = (const float*)d_in[8];
  const float* g1 = (const float*)d_in[9];
  const float* be1 = (const float*)d_in[10];
  const float* g2 = (const float*)d_in[11];
  const float* be2 = (const float*)d_in[12];

  char* ws = (char*)d_ws;
  const size_t MB = 1024 * 1024;
  float* x1 = (float*)(ws + 0);          // 32MB, becomes x2 in-place after OPROJ
  u16* h = (u16*)(ws + 32 * MB);         // 16MB (reused as h2)
  u16* q = (u16*)(ws + 48 * MB);         // 16MB
  u16* k = (u16*)(ws + 64 * MB);         // 16MB
  u16* vt = (u16*)(ws + 80 * MB);        // 16MB
  u16* o = (u16*)(ws + 96 * MB);         // 16MB
  u16* f = (u16*)(ws + 48 * MB);         // 48MB, aliases q/k/vt (dead after attn)
  u16* wqkv = (u16*)(ws + 112 * MB);     // 6MB
  u16* wo = (u16*)(ws + 118 * MB);       // 2MB
  u16* w1t = (u16*)(ws + 120 * MB);      // 6MB
  u16* w2t = (u16*)(ws + 126 * MB);      // 6MB -> 132MB total
  float* out = (float*)d_out;

  dim3 tb(32, 8);
  tconv<<<dim3(32, 32), tb, 0, stream>>>(Wq, wqkv, 1024, 1024);
  tconv<<<dim3(32, 32), tb, 0, stream>>>(Wk, wqkv + 1024 * 1024, 1024, 1024);
  tconv<<<dim3(32, 32), tb, 0, stream>>>(Wv, wqkv + 2 * 1024 * 1024, 1024, 1024);
  tconv<<<dim3(32, 32), tb, 0, stream>>>(Wo, wo, 1024, 1024);
  tconv<<<dim3(96, 32), tb, 0, stream>>>(W1, w1t, 1024, 3072);
  tconv<<<dim3(32, 96), tb, 0, stream>>>(W2, w2t, 3072, 1024);

  ln_row<true><<<8192, 256, 0, stream>>>(x, g1, be1, x1, h);

  gemm8p<EPI_QKV><<<384, 512, 0, stream>>>(h, wqkv, 1024, 12,
                                           nullptr, nullptr, nullptr, nullptr,
                                           q, k, vt);
  attn_fwd<<<1024, 256, 0, stream>>>(q, k, vt, o);

  gemm8p<EPI_OPROJ><<<128, 512, 0, stream>>>(o, wo, 1024, 4,
                                             nullptr, x1, x1, nullptr,
                                             nullptr, nullptr, nullptr);
  ln_row<false><<<8192, 256, 0, stream>>>(x1, g2, be2, nullptr, h);

  gemm8p<EPI_FFN1><<<384, 512, 0, stream>>>(h, w1t, 1024, 12,
                                            b1, nullptr, nullptr, f,
                                            nullptr, nullptr, nullptr);
  gemm8p<EPI_FFN2><<<128, 512, 0, stream>>>(f, w2t, 3072, 4,
                                            b2, x1, out, nullptr,
                                            nullptr, nullptr, nullptr);
}

// Round 9
// 471.471 us; speedup vs baseline: 1.0446x; 1.0446x over previous
//
#include <hip/hip_runtime.h>

typedef unsigned short u16;
typedef __bf16 bf16x8 __attribute__((ext_vector_type(8)));
typedef float f32x4 __attribute__((ext_vector_type(4)));

__device__ __forceinline__ u16 f2bf(float f) {
  unsigned u = __builtin_bit_cast(unsigned, f);
  u += 0x7FFFu + ((u >> 16) & 1u);
  return (u16)(u >> 16);
}

#define GLOAD16(g, l) __builtin_amdgcn_global_load_lds( \
    (const __attribute__((address_space(1))) unsigned int*)(const void*)(g), \
    (__attribute__((address_space(3))) unsigned int*)(void*)(l), 16, 0, 0)

// swizzled u16 index of 16B-chunk c (0..7) in row r of a 64-u16-wide LDS tile
#define SW(r, c) (((r) << 6) + ((((c) ^ ((r) & 7))) << 3))

// ---------------------------------------------------------------- transpose + f32->bf16
__global__ __launch_bounds__(256) void tconv(const float* __restrict__ W,
                                             u16* __restrict__ Wt, int K, int N) {
  __shared__ float t[32][33];
  int n0 = blockIdx.x * 32, k0 = blockIdx.y * 32;
  int tx = threadIdx.x, ty = threadIdx.y;
#pragma unroll
  for (int j = 0; j < 4; ++j)
    t[ty + j * 8][tx] = W[(size_t)(k0 + ty + j * 8) * N + n0 + tx];
  __syncthreads();
#pragma unroll
  for (int j = 0; j < 4; ++j)
    Wt[(size_t)(n0 + ty + j * 8) * K + k0 + tx] = f2bf(t[tx][ty + j * 8]);
}

// ---------------------------------------------------------------- posenc + layernorm
template <bool PE>
__global__ __launch_bounds__(256) void ln_row(const float* __restrict__ in,
                                              const float* __restrict__ g,
                                              const float* __restrict__ be,
                                              float* __restrict__ xout,
                                              u16* __restrict__ hout) {
  const int row = blockIdx.x;
  const int tid = threadIdx.x;
  const int s = row & 2047;
  float4 xv = *(const float4*)&in[(size_t)row * 1024 + tid * 4];
  float vals[4];
  const float* xp = (const float*)&xv;
#pragma unroll
  for (int j = 0; j < 4; ++j) {
    float v = xp[j];
    if (PE) {
      int d = tid * 4 + j;
      float freq = powf(10000.f, -2.f * (float)d * (1.f / 1024.f));
      float ang = (float)s * freq;
      v += (d & 1) ? cosf(ang) : sinf(ang);
    }
    vals[j] = v;
  }
  if (PE) {
    float4 st;
    float* sp = (float*)&st;
#pragma unroll
    for (int j = 0; j < 4; ++j) sp[j] = vals[j];
    *(float4*)&xout[(size_t)row * 1024 + tid * 4] = st;
  }
  float sum = vals[0] + vals[1] + vals[2] + vals[3];
  float sq = vals[0] * vals[0] + vals[1] * vals[1] + vals[2] * vals[2] + vals[3] * vals[3];
#pragma unroll
  for (int d = 1; d < 64; d <<= 1) {
    sum += __shfl_xor(sum, d);
    sq += __shfl_xor(sq, d);
  }
  __shared__ float red[8];
  int wave = tid >> 6, lane = tid & 63;
  if (lane == 0) { red[wave] = sum; red[4 + wave] = sq; }
  __syncthreads();
  sum = red[0] + red[1] + red[2] + red[3];
  sq = red[4] + red[5] + red[6] + red[7];
  float mu = sum * (1.f / 1024.f);
  float var = sq * (1.f / 1024.f) - mu * mu;
  float rv = rsqrtf(var + 1e-5f);
#pragma unroll
  for (int j = 0; j < 4; ++j) {
    int d = tid * 4 + j;
    hout[(size_t)row * 1024 + d] = f2bf((vals[j] - mu) * rv * g[d] + be[d]);
  }
}

// ---------------------------------------------------------------- GEMM: 8-phase, de-pinned
// C = A @ Bt^T.  Tile 256x256, BK=64 (2 kk-halves), 512 thr = 8 waves (2M x 4N).
// Per-wave out 128x64 = acc[8][4].  LDS 128KB: [2 dbuf][2 kk][128 lds-rows][64] A and B.
// Phase: {ds_read frags; stage 1 half (2 gloads); setprio+16 MFMA; [vmcnt(4) @ p3/p7];
// ONE s_barrier + compiler memory fence}.  No sched_barrier / no explicit lgkmcnt --
// the compiler schedules reads/MFMA/staging within the phase (m141 lesson).
// Safety: reads of a slab complete before their MFMAs (compiler lgkm waits), hence
// before barrier(p); conflicting re-stage issues after barrier(p).  Landing
// publication: per-wave vmcnt(4) BEFORE the barrier at p3/p7.
#define EPI_QKV 0
#define EPI_OPROJ 1
#define EPI_FFN1 2
#define EPI_FFN2 3

template <int EPI>
__global__ __launch_bounds__(512, 1) void gemm8p(
    const u16* __restrict__ A, const u16* __restrict__ Bt, int K, int ntx,
    const float* __restrict__ bias, const float* __restrict__ resid,
    float* __restrict__ outf, u16* __restrict__ outb,
    u16* __restrict__ oq, u16* __restrict__ okk, u16* __restrict__ ovt) {
  __shared__ __align__(16) u16 Als[2][2][8192];
  __shared__ __align__(16) u16 Bls[2][2][8192];
  const int tid = threadIdx.x;
  const int wave = tid >> 6, lane = tid & 63;
  const int wm = wave >> 2, wn = wave & 3;
  const int lrow = lane & 15, lhi = lane >> 4;
  const int nwg = gridDim.x;
  const int wid = ((int)blockIdx.x & 7) * (nwg >> 3) + ((int)blockIdx.x >> 3);
  const int m0 = (wid / ntx) * 256, n0 = (wid % ntx) * 256;
  const int NT = K >> 6, NIT = NT >> 1;

  // staging geometry: lds row j = wave*8 + (lane>>3) (+64 for second gload); slot
  // lane&7 holds global (row 2j + (u>>2), col-chunk (u&3)), u = (lane&7)^(j&7)
  const int u = (lane & 7) ^ ((lane >> 3) & 7);
  const int srow2 = wave * 8 + (lane >> 3);
  const size_t aR0 = (size_t)(m0 + 2 * srow2 + (u >> 2)) * K + (u & 3) * 8;
  const size_t aR1 = aR0 + (size_t)128 * K;
  const size_t bR0 = (size_t)(n0 + 2 * srow2 + (u >> 2)) * K + (u & 3) * 8;
  const size_t bR1 = bR0 + (size_t)128 * K;
  // fragment read: global row r -> lds row j=r>>1, slot ((r&1)*4+lhi)^(j&7)
  const int jchk = ((lrow >> 1) << 6) + (((((lrow & 1) << 2) + lhi) ^ ((lrow >> 1) & 7)) << 3);

#define STG_A(b, kk, kof) do { \
    GLOAD16(A + aR0 + (kof) + (kk) * 32, &Als[b][kk][wave * 512]); \
    GLOAD16(A + aR1 + (kof) + (kk) * 32, &Als[b][kk][4096 + wave * 512]); \
  } while (0)
#define STG_B(b, kk, kof) do { \
    GLOAD16(Bt + bR0 + (kof) + (kk) * 32, &Bls[b][kk][wave * 512]); \
    GLOAD16(Bt + bR1 + (kof) + (kk) * 32, &Bls[b][kk][4096 + wave * 512]); \
  } while (0)
#define VM4 asm volatile("s_waitcnt vmcnt(4)" ::: "memory")

  f32x4 acc[8][4] = {};
  bf16x8 afr[4], bfr[4];

#define PHASE(TB, KK, MH, READB, STGSTMT, ENDVM) do { \
    if (READB) { \
      _Pragma("unroll") \
      for (int nf = 0; nf < 4; ++nf) \
        bfr[nf] = *(const bf16x8*)&Bls[TB][KK][wn * 2048 + nf * 512 + jchk]; \
    } \
    _Pragma("unroll") \
    for (int a = 0; a < 4; ++a) \
      afr[a] = *(const bf16x8*)&Als[TB][KK][wm * 4096 + ((MH) * 4 + a) * 512 + jchk]; \
    STGSTMT; \
    __builtin_amdgcn_s_setprio(1); \
    _Pragma("unroll") \
    for (int a = 0; a < 4; ++a) \
      _Pragma("unroll") \
      for (int nf = 0; nf < 4; ++nf) \
        acc[(MH) * 4 + a][nf] = \
            __builtin_amdgcn_mfma_f32_16x16x32_bf16(afr[a], bfr[nf], acc[(MH) * 4 + a][nf], 0, 0, 0); \
    __builtin_amdgcn_s_setprio(0); \
    ENDVM; \
    __builtin_amdgcn_s_barrier(); \
    asm volatile("" ::: "memory"); \
  } while (0)

  // prologue: tile0 (both kk) + tile1 kk0; vmcnt(4) leaves tile1-kk0 in flight
  STG_A(0, 0, 0); STG_B(0, 0, 0);
  STG_A(0, 1, 0); STG_B(0, 1, 0);
  STG_A(1, 0, 64); STG_B(1, 0, 64);
  VM4;
  __builtin_amdgcn_s_barrier();
  asm volatile("" ::: "memory");

  for (int it = 0; it < NIT; ++it) {
    const int kof1 = (2 * it + 1) << 6;
    const int t2 = 2 * it + 2, t3 = 2 * it + 3;
    const int kof2 = (t2 < NT) ? (t2 << 6) : 0;
    const int kof3 = (t3 < NT) ? (t3 << 6) : 0;
    PHASE(0, 0, 0, 1, STG_A(1, 1, kof1), );
    PHASE(0, 0, 1, 0, STG_B(1, 1, kof1), );
    PHASE(0, 1, 0, 1, STG_A(0, 0, kof2), );
    PHASE(0, 1, 1, 0, STG_B(0, 0, kof2), VM4);
    PHASE(1, 0, 0, 1, STG_A(0, 1, kof2), );
    PHASE(1, 0, 1, 0, STG_B(0, 1, kof2), );
    PHASE(1, 1, 0, 1, STG_A(1, 0, kof3), );
    PHASE(1, 1, 1, 0, STG_B(1, 0, kof3), VM4);
  }
  asm volatile("s_waitcnt vmcnt(0)" ::: "memory");

#pragma unroll
  for (int mf = 0; mf < 8; ++mf) {
#pragma unroll
    for (int nf = 0; nf < 4; ++nf) {
#pragma unroll
      for (int i = 0; i < 4; ++i) {
        int row = m0 + wm * 128 + mf * 16 + lhi * 4 + i;
        int col = n0 + wn * 64 + nf * 16 + lrow;
        float v = acc[mf][nf][i];
        if (EPI == EPI_QKV) {
          int which = col >> 10, c = col & 1023;
          int h = c >> 6, hd = c & 63;
          int b = row >> 11, s = row & 2047;
          size_t qk = (((size_t)(b * 16 + h) * 2048 + s) << 6) + hd;
          if (which == 0) oq[qk] = f2bf(v * 0.03125f);
          else if (which == 1) okk[qk] = f2bf(v);
          else ovt[((size_t)(b * 16 + h) * 64 + hd) * 2048 + s] = f2bf(v);
        } else if (EPI == EPI_OPROJ) {
          size_t idx = (size_t)row * 1024 + col;
          outf[idx] = v + resid[idx];
        } else if (EPI == EPI_FFN1) {
          float t = v + bias[col];
          t = t > 0.f ? t : 0.01f * t;
          outb[(size_t)row * 3072 + col] = f2bf(t);
        } else {  // FFN2
          size_t idx = (size_t)row * 1024 + col;
          outf[idx] = v + bias[col] + resid[idx];
        }
      }
    }
  }
#undef PHASE
#undef STG_A
#undef STG_B
#undef VM4
}

// ---------------------------------------------------------------- flash attention (R6, unchanged)
__global__ __launch_bounds__(256, 3) void attn_fwd(const u16* __restrict__ qb,
                                                   const u16* __restrict__ kbuf,
                                                   const u16* __restrict__ vtb,
                                                   u16* __restrict__ ob) {
  __shared__ __align__(16) u16 Kl[2][64 * 64];
  __shared__ __align__(16) u16 Vl[2][64 * 64];
  __shared__ __align__(16) u16 Pl[128 * 64];
  const int tid = threadIdx.x, wave = tid >> 6, lane = tid & 63;
  const int wid = (blockIdx.x & 7) * 128 + (blockIdx.x >> 3);
  const int bh = wid >> 4, qt = wid & 15;
  const int lrow = lane & 15, lhi = lane >> 4;
  const u16* Qg = qb + (((size_t)bh * 2048 + qt * 128) << 6);
  const u16* Kg = kbuf + ((size_t)bh * 2048 << 6);
  const u16* Vg = vtb + (size_t)bh * 64 * 2048;
  const int srow = tid >> 3;
  const int swsrc = ((tid & 7) ^ (srow & 7)) * 8;

#pragma unroll
  for (int j = 0; j < 4; ++j)
    GLOAD16(Qg + (size_t)(srow + j * 32) * 64 + swsrc, &Pl[j * 2048 + wave * 512]);
#pragma unroll
  for (int j = 0; j < 2; ++j) {
    int r = srow + j * 32;
    GLOAD16(Kg + (size_t)r * 64 + swsrc, &Kl[0][j * 2048 + wave * 512]);
    GLOAD16(Vg + (size_t)r * 2048 + swsrc, &Vl[0][j * 2048 + wave * 512]);
  }
  __syncthreads();

  bf16x8 qf[2][2];
#pragma unroll
  for (int m = 0; m < 2; ++m)
#pragma unroll
    for (int kk = 0; kk < 2; ++kk)
      qf[m][kk] = *(const bf16x8*)&Pl[SW(wave * 32 + m * 16 + lrow, kk * 4 + lhi)];

  f32x4 oacc[2][4] = {};
  float lsum[8];
#pragma unroll
  for (int i = 0; i < 8; ++i) lsum[i] = 0.f;

  int cur = 0;
  for (int kv = 0; kv < 2048; kv += 64) {
    if (kv) __syncthreads();
    if (kv + 64 < 2048) {
#pragma unroll
      for (int j = 0; j < 2; ++j) {
        int r = srow + j * 32;
        GLOAD16(Kg + (size_t)(kv + 64 + r) * 64 + swsrc, &Kl[cur ^ 1][j * 2048 + wave * 512]);
        GLOAD16(Vg + (size_t)r * 2048 + kv + 64 + swsrc, &Vl[cur ^ 1][j * 2048 + wave * 512]);
      }
    }

    f32x4 sf[2][4] = {};
#pragma unroll
    for (int n = 0; n < 4; ++n) {
#pragma unroll
      for (int kk = 0; kk < 2; ++kk) {
        bf16x8 kf = *(const bf16x8*)&Kl[cur][SW(n * 16 + lrow, kk * 4 + lhi)];
        sf[0][n] = __builtin_amdgcn_mfma_f32_16x16x32_bf16(qf[0][kk], kf, sf[0][n], 0, 0, 0);
        sf[1][n] = __builtin_amdgcn_mfma_f32_16x16x32_bf16(qf[1][kk], kf, sf[1][n], 0, 0, 0);
      }
    }
#pragma unroll
    for (int m = 0; m < 2; ++m) {
#pragma unroll
      for (int i = 0; i < 4; ++i) {
        float rs = 0.f;
#pragma unroll
        for (int n = 0; n < 4; ++n) {
          float p = __expf(sf[m][n][i]);
          sf[m][n][i] = p;
          rs += p;
        }
        lsum[m * 4 + i] += rs;
      }
    }
#pragma unroll
    for (int m = 0; m < 2; ++m)
#pragma unroll
      for (int n = 0; n < 4; ++n)
#pragma unroll
        for (int i = 0; i < 4; ++i) {
          int pr = wave * 32 + m * 16 + lhi * 4 + i;
          Pl[SW(pr, n * 2 + (lrow >> 3)) + (lrow & 7)] = f2bf(sf[m][n][i]);
        }
#pragma unroll
    for (int kk = 0; kk < 2; ++kk) {
      bf16x8 pf0 = *(const bf16x8*)&Pl[SW(wave * 32 + 0 + lrow, kk * 4 + lhi)];
      bf16x8 pf1 = *(const bf16x8*)&Pl[SW(wave * 32 + 16 + lrow, kk * 4 + lhi)];
#pragma unroll
      for (int n = 0; n < 4; ++n) {
        bf16x8 vf = *(const bf16x8*)&Vl[cur][SW(n * 16 + lrow, kk * 4 + lhi)];
        oacc[0][n] = __builtin_amdgcn_mfma_f32_16x16x32_bf16(pf0, vf, oacc[0][n], 0, 0, 0);
        oacc[1][n] = __builtin_amdgcn_mfma_f32_16x16x32_bf16(pf1, vf, oacc[1][n], 0, 0, 0);
      }
    }
    cur ^= 1;
  }

#pragma unroll
  for (int idx = 0; idx < 8; ++idx)
#pragma unroll
    for (int d = 1; d < 16; d <<= 1)
      lsum[idx] += __shfl_xor(lsum[idx], d, 16);

  const int b = bh >> 4, h = bh & 15;
#pragma unroll
  for (int m = 0; m < 2; ++m)
#pragma unroll
    for (int i = 0; i < 4; ++i) {
      int qrow = qt * 128 + wave * 32 + m * 16 + lhi * 4 + i;
      float inv = 1.f / lsum[m * 4 + i];
#pragma unroll
      for (int n = 0; n < 4; ++n) {
        int hd = n * 16 + lrow;
        ob[((size_t)(b * 2048 + qrow)) * 1024 + h * 64 + hd] = f2bf(oacc[m][n][i] * inv);
      }
    }
}

// ---------------------------------------------------------------- launch
extern "C" void kernel_launch(void* const* d_in, const int* in_sizes, int n_in,
                              void* d_out, int out_size, void* d_ws, size_t ws_size,
                              hipStream_t stream) {
  const float* x = (const float*)d_in[0];
  const float* Wq = (const float*)d_in[1];
  const float* Wk = (const float*)d_in[2];
  const float* Wv = (const float*)d_in[3];
  const float* Wo = (const float*)d_in[4];
  const float* W1 = (const float*)d_in[5];
  const float* b1 = (const float*)d_in[6];
  const float* W2 = (const float*)d_in[7];
  const float* b2 = (const float*)d_in[8];
  const float* g1 = (const float*)d_in[9];
  const float* be1 = (const float*)d_in[10];
  const float* g2 = (const float*)d_in[11];
  const float* be2 = (const float*)d_in[12];

  char* ws = (char*)d_ws;
  const size_t MB = 1024 * 1024;
  float* x1 = (float*)(ws + 0);          // 32MB, becomes x2 in-place after OPROJ
  u16* h = (u16*)(ws + 32 * MB);         // 16MB (reused as h2)
  u16* q = (u16*)(ws + 48 * MB);         // 16MB
  u16* k = (u16*)(ws + 64 * MB);         // 16MB
  u16* vt = (u16*)(ws + 80 * MB);        // 16MB
  u16* o = (u16*)(ws + 96 * MB);         // 16MB
  u16* f = (u16*)(ws + 48 * MB);         // 48MB, aliases q/k/vt (dead after attn)
  u16* wqkv = (u16*)(ws + 112 * MB);     // 6MB
  u16* wo = (u16*)(ws + 118 * MB);       // 2MB
  u16* w1t = (u16*)(ws + 120 * MB);      // 6MB
  u16* w2t = (u16*)(ws + 126 * MB);      // 6MB -> 132MB total
  float* out = (float*)d_out;

  dim3 tb(32, 8);
  tconv<<<dim3(32, 32), tb, 0, stream>>>(Wq, wqkv, 1024, 1024);
  tconv<<<dim3(32, 32), tb, 0, stream>>>(Wk, wqkv + 1024 * 1024, 1024, 1024);
  tconv<<<dim3(32, 32), tb, 0, stream>>>(Wv, wqkv + 2 * 1024 * 1024, 1024, 1024);
  tconv<<<dim3(32, 32), tb, 0, stream>>>(Wo, wo, 1024, 1024);
  tconv<<<dim3(96, 32), tb, 0, stream>>>(W1, w1t, 1024, 3072);
  tconv<<<dim3(32, 96), tb, 0, stream>>>(W2, w2t, 3072, 1024);

  ln_row<true><<<8192, 256, 0, stream>>>(x, g1, be1, x1, h);

  gemm8p<EPI_QKV><<<384, 512, 0, stream>>>(h, wqkv, 1024, 12,
                                           nullptr, nullptr, nullptr, nullptr,
                                           q, k, vt);
  attn_fwd<<<1024, 256, 0, stream>>>(q, k, vt, o);

  gemm8p<EPI_OPROJ><<<128, 512, 0, stream>>>(o, wo, 1024, 4,
                                             nullptr, x1, x1, nullptr,
                                             nullptr, nullptr, nullptr);
  ln_row<false><<<8192, 256, 0, stream>>>(x1, g2, be2, nullptr, h);

  gemm8p<EPI_FFN1><<<384, 512, 0, stream>>>(h, w1t, 1024, 12,
                                            b1, nullptr, nullptr, f,
                                            nullptr, nullptr, nullptr);
  gemm8p<EPI_FFN2><<<128, 512, 0, stream>>>(f, w2t, 3072, 4,
                                            b2, x1, out, nullptr,
                                            nullptr, nullptr, nullptr);
}

// Round 10
// 433.792 us; speedup vs baseline: 1.1353x; 1.0869x over previous
//
#include <hip/hip_runtime.h>

typedef unsigned short u16;
typedef __bf16 bf16x8 __attribute__((ext_vector_type(8)));
typedef float f32x4 __attribute__((ext_vector_type(4)));

__device__ __forceinline__ u16 f2bf(float f) {
  unsigned u = __builtin_bit_cast(unsigned, f);
  u += 0x7FFFu + ((u >> 16) & 1u);
  return (u16)(u >> 16);
}

#define GLOAD16(g, l) __builtin_amdgcn_global_load_lds( \
    (const __attribute__((address_space(1))) unsigned int*)(const void*)(g), \
    (__attribute__((address_space(3))) unsigned int*)(void*)(l), 16, 0, 0)

// swizzled u16 index of 16B-chunk c (0..7) in row r of a 64-u16-wide LDS tile
#define SW(r, c) (((r) << 6) + ((((c) ^ ((r) & 7))) << 3))

// ---------------------------------------------------------------- transpose + f32->bf16
__global__ __launch_bounds__(256) void tconv(const float* __restrict__ W,
                                             u16* __restrict__ Wt, int K, int N) {
  __shared__ float t[32][33];
  int n0 = blockIdx.x * 32, k0 = blockIdx.y * 32;
  int tx = threadIdx.x, ty = threadIdx.y;
#pragma unroll
  for (int j = 0; j < 4; ++j)
    t[ty + j * 8][tx] = W[(size_t)(k0 + ty + j * 8) * N + n0 + tx];
  __syncthreads();
#pragma unroll
  for (int j = 0; j < 4; ++j)
    Wt[(size_t)(n0 + ty + j * 8) * K + k0 + tx] = f2bf(t[tx][ty + j * 8]);
}

// ---------------------------------------------------------------- posenc + layernorm
template <bool PE>
__global__ __launch_bounds__(256) void ln_row(const float* __restrict__ in,
                                              const float* __restrict__ g,
                                              const float* __restrict__ be,
                                              float* __restrict__ xout,
                                              u16* __restrict__ hout) {
  const int row = blockIdx.x;
  const int tid = threadIdx.x;
  const int s = row & 2047;
  float4 xv = *(const float4*)&in[(size_t)row * 1024 + tid * 4];
  float vals[4];
  const float* xp = (const float*)&xv;
#pragma unroll
  for (int j = 0; j < 4; ++j) {
    float v = xp[j];
    if (PE) {
      int d = tid * 4 + j;
      float freq = powf(10000.f, -2.f * (float)d * (1.f / 1024.f));
      float ang = (float)s * freq;
      v += (d & 1) ? cosf(ang) : sinf(ang);
    }
    vals[j] = v;
  }
  if (PE) {
    float4 st;
    float* sp = (float*)&st;
#pragma unroll
    for (int j = 0; j < 4; ++j) sp[j] = vals[j];
    *(float4*)&xout[(size_t)row * 1024 + tid * 4] = st;
  }
  float sum = vals[0] + vals[1] + vals[2] + vals[3];
  float sq = vals[0] * vals[0] + vals[1] * vals[1] + vals[2] * vals[2] + vals[3] * vals[3];
#pragma unroll
  for (int d = 1; d < 64; d <<= 1) {
    sum += __shfl_xor(sum, d);
    sq += __shfl_xor(sq, d);
  }
  __shared__ float red[8];
  int wave = tid >> 6, lane = tid & 63;
  if (lane == 0) { red[wave] = sum; red[4 + wave] = sq; }
  __syncthreads();
  sum = red[0] + red[1] + red[2] + red[3];
  sq = red[4] + red[5] + red[6] + red[7];
  float mu = sum * (1.f / 1024.f);
  float var = sq * (1.f / 1024.f) - mu * mu;
  float rv = rsqrtf(var + 1e-5f);
#pragma unroll
  for (int j = 0; j < 4; ++j) {
    int d = tid * 4 + j;
    hout[(size_t)row * 1024 + d] = f2bf((vals[j] - mu) * rv * g[d] + be[d]);
  }
}

// ---------------------------------------------------------------- GEMM  C = A @ Bt^T
// A: M x K bf16 row-major.  Bt: N x K bf16 row-major.  128x128 tile, BK=64, 4 waves.
// R6 structure with BK doubled: 2 barriers per 64-K (32 MFMA/wave per epoch),
// 8 in-flight gloads per thread per epoch.  64-u16 LDS rows need the XOR
// swizzle (G4 D=128B case): staging pre-swizzles the GLOBAL source chunk
// (rule #21), reads use SW() -- geometry identical to attn (measured 0 confl).
#define EPI_QKV 0
#define EPI_OPROJ 1
#define EPI_FFN1 2
#define EPI_FFN2 3

template <int EPI>
__global__ __launch_bounds__(256, 2) void gemm_bt(
    const u16* __restrict__ A, const u16* __restrict__ Bt, int M, int N, int K,
    const float* __restrict__ bias, const float* __restrict__ resid,
    float* __restrict__ outf, u16* __restrict__ outb,
    u16* __restrict__ oq, u16* __restrict__ okk, u16* __restrict__ ovt) {
  __shared__ __align__(16) u16 As[128 * 64];
  __shared__ __align__(16) u16 Bs[128 * 64];
  const int tid = threadIdx.x;
  const int wave = tid >> 6, lane = tid & 63;
  const int m0 = blockIdx.y * 128, n0 = blockIdx.x * 128;
  const int lrow = lane & 15, lhi = lane >> 4;
  const int wr = (wave >> 1) * 64, wc = (wave & 1) * 64;
  const int srow = tid >> 3;                       // staging row 0..31 (of each 32-row group)
  const int swsrc = ((tid & 7) ^ (srow & 7)) * 8;  // pre-swizzled source chunk
  const u16* Ag = A + (size_t)(m0 + srow) * K + swsrc;
  const u16* Bg = Bt + (size_t)(n0 + srow) * K + swsrc;

  f32x4 acc[4][4] = {};

  for (int kt = 0; kt < K; kt += 64) {
#pragma unroll
    for (int j = 0; j < 4; ++j) {
      GLOAD16(Ag + (size_t)(j * 32) * K + kt, &As[j * 2048 + wave * 512]);
      GLOAD16(Bg + (size_t)(j * 32) * K + kt, &Bs[j * 2048 + wave * 512]);
    }
    __syncthreads();
    bf16x8 af[2][4], bfr[2][4];
#pragma unroll
    for (int kk = 0; kk < 2; ++kk) {
#pragma unroll
      for (int m = 0; m < 4; ++m)
        af[kk][m] = *(const bf16x8*)&As[SW(wr + m * 16 + lrow, kk * 4 + lhi)];
#pragma unroll
      for (int n = 0; n < 4; ++n)
        bfr[kk][n] = *(const bf16x8*)&Bs[SW(wc + n * 16 + lrow, kk * 4 + lhi)];
    }
#pragma unroll
    for (int kk = 0; kk < 2; ++kk)
#pragma unroll
      for (int m = 0; m < 4; ++m)
#pragma unroll
        for (int n = 0; n < 4; ++n)
          acc[m][n] = __builtin_amdgcn_mfma_f32_16x16x32_bf16(af[kk][m], bfr[kk][n], acc[m][n], 0, 0, 0);
    __syncthreads();
  }

#pragma unroll
  for (int m = 0; m < 4; ++m) {
#pragma unroll
    for (int n = 0; n < 4; ++n) {
#pragma unroll
      for (int i = 0; i < 4; ++i) {
        int row = m0 + wr + m * 16 + lhi * 4 + i;
        int col = n0 + wc + n * 16 + lrow;
        float v = acc[m][n][i];
        if (EPI == EPI_QKV) {
          int which = col >> 10, c = col & 1023;
          int h = c >> 6, hd = c & 63;
          int b = row >> 11, s = row & 2047;
          size_t qk = (((size_t)(b * 16 + h) * 2048 + s) << 6) + hd;
          if (which == 0) oq[qk] = f2bf(v * 0.03125f);
          else if (which == 1) okk[qk] = f2bf(v);
          else ovt[((size_t)(b * 16 + h) * 64 + hd) * 2048 + s] = f2bf(v);
        } else if (EPI == EPI_OPROJ) {
          size_t idx = (size_t)row * 1024 + col;
          outf[idx] = v + resid[idx];
        } else if (EPI == EPI_FFN1) {
          float t = v + bias[col];
          t = t > 0.f ? t : 0.01f * t;
          outb[(size_t)row * 3072 + col] = f2bf(t);
        } else {  // FFN2
          size_t idx = (size_t)row * 1024 + col;
          outf[idx] = v + bias[col] + resid[idx];
        }
      }
    }
  }
}

// ---------------------------------------------------------------- flash attention (R6, unchanged)
__global__ __launch_bounds__(256, 3) void attn_fwd(const u16* __restrict__ qb,
                                                   const u16* __restrict__ kbuf,
                                                   const u16* __restrict__ vtb,
                                                   u16* __restrict__ ob) {
  __shared__ __align__(16) u16 Kl[2][64 * 64];
  __shared__ __align__(16) u16 Vl[2][64 * 64];
  __shared__ __align__(16) u16 Pl[128 * 64];
  const int tid = threadIdx.x, wave = tid >> 6, lane = tid & 63;
  const int wid = (blockIdx.x & 7) * 128 + (blockIdx.x >> 3);
  const int bh = wid >> 4, qt = wid & 15;
  const int lrow = lane & 15, lhi = lane >> 4;
  const u16* Qg = qb + (((size_t)bh * 2048 + qt * 128) << 6);
  const u16* Kg = kbuf + ((size_t)bh * 2048 << 6);
  const u16* Vg = vtb + (size_t)bh * 64 * 2048;
  const int srow = tid >> 3;
  const int swsrc = ((tid & 7) ^ (srow & 7)) * 8;

#pragma unroll
  for (int j = 0; j < 4; ++j)
    GLOAD16(Qg + (size_t)(srow + j * 32) * 64 + swsrc, &Pl[j * 2048 + wave * 512]);
#pragma unroll
  for (int j = 0; j < 2; ++j) {
    int r = srow + j * 32;
    GLOAD16(Kg + (size_t)r * 64 + swsrc, &Kl[0][j * 2048 + wave * 512]);
    GLOAD16(Vg + (size_t)r * 2048 + swsrc, &Vl[0][j * 2048 + wave * 512]);
  }
  __syncthreads();

  bf16x8 qf[2][2];
#pragma unroll
  for (int m = 0; m < 2; ++m)
#pragma unroll
    for (int kk = 0; kk < 2; ++kk)
      qf[m][kk] = *(const bf16x8*)&Pl[SW(wave * 32 + m * 16 + lrow, kk * 4 + lhi)];

  f32x4 oacc[2][4] = {};
  float lsum[8];
#pragma unroll
  for (int i = 0; i < 8; ++i) lsum[i] = 0.f;

  int cur = 0;
  for (int kv = 0; kv < 2048; kv += 64) {
    if (kv) __syncthreads();
    if (kv + 64 < 2048) {
#pragma unroll
      for (int j = 0; j < 2; ++j) {
        int r = srow + j * 32;
        GLOAD16(Kg + (size_t)(kv + 64 + r) * 64 + swsrc, &Kl[cur ^ 1][j * 2048 + wave * 512]);
        GLOAD16(Vg + (size_t)r * 2048 + kv + 64 + swsrc, &Vl[cur ^ 1][j * 2048 + wave * 512]);
      }
    }

    f32x4 sf[2][4] = {};
#pragma unroll
    for (int n = 0; n < 4; ++n) {
#pragma unroll
      for (int kk = 0; kk < 2; ++kk) {
        bf16x8 kf = *(const bf16x8*)&Kl[cur][SW(n * 16 + lrow, kk * 4 + lhi)];
        sf[0][n] = __builtin_amdgcn_mfma_f32_16x16x32_bf16(qf[0][kk], kf, sf[0][n], 0, 0, 0);
        sf[1][n] = __builtin_amdgcn_mfma_f32_16x16x32_bf16(qf[1][kk], kf, sf[1][n], 0, 0, 0);
      }
    }
#pragma unroll
    for (int m = 0; m < 2; ++m) {
#pragma unroll
      for (int i = 0; i < 4; ++i) {
        float rs = 0.f;
#pragma unroll
        for (int n = 0; n < 4; ++n) {
          float p = __expf(sf[m][n][i]);
          sf[m][n][i] = p;
          rs += p;
        }
        lsum[m * 4 + i] += rs;
      }
    }
#pragma unroll
    for (int m = 0; m < 2; ++m)
#pragma unroll
      for (int n = 0; n < 4; ++n)
#pragma unroll
        for (int i = 0; i < 4; ++i) {
          int pr = wave * 32 + m * 16 + lhi * 4 + i;
          Pl[SW(pr, n * 2 + (lrow >> 3)) + (lrow & 7)] = f2bf(sf[m][n][i]);
        }
#pragma unroll
    for (int kk = 0; kk < 2; ++kk) {
      bf16x8 pf0 = *(const bf16x8*)&Pl[SW(wave * 32 + 0 + lrow, kk * 4 + lhi)];
      bf16x8 pf1 = *(const bf16x8*)&Pl[SW(wave * 32 + 16 + lrow, kk * 4 + lhi)];
#pragma unroll
      for (int n = 0; n < 4; ++n) {
        bf16x8 vf = *(const bf16x8*)&Vl[cur][SW(n * 16 + lrow, kk * 4 + lhi)];
        oacc[0][n] = __builtin_amdgcn_mfma_f32_16x16x32_bf16(pf0, vf, oacc[0][n], 0, 0, 0);
        oacc[1][n] = __builtin_amdgcn_mfma_f32_16x16x32_bf16(pf1, vf, oacc[1][n], 0, 0, 0);
      }
    }
    cur ^= 1;
  }

#pragma unroll
  for (int idx = 0; idx < 8; ++idx)
#pragma unroll
    for (int d = 1; d < 16; d <<= 1)
      lsum[idx] += __shfl_xor(lsum[idx], d, 16);

  const int b = bh >> 4, h = bh & 15;
#pragma unroll
  for (int m = 0; m < 2; ++m)
#pragma unroll
    for (int i = 0; i < 4; ++i) {
      int qrow = qt * 128 + wave * 32 + m * 16 + lhi * 4 + i;
      float inv = 1.f / lsum[m * 4 + i];
#pragma unroll
      for (int n = 0; n < 4; ++n) {
        int hd = n * 16 + lrow;
        ob[((size_t)(b * 2048 + qrow)) * 1024 + h * 64 + hd] = f2bf(oacc[m][n][i] * inv);
      }
    }
}

// ---------------------------------------------------------------- launch
extern "C" void kernel_launch(void* const* d_in, const int* in_sizes, int n_in,
                              void* d_out, int out_size, void* d_ws, size_t ws_size,
                              hipStream_t stream) {
  const float* x = (const float*)d_in[0];
  const float* Wq = (const float*)d_in[1];
  const float* Wk = (const float*)d_in[2];
  const float* Wv = (const float*)d_in[3];
  const float* Wo = (const float*)d_in[4];
  const float* W1 = (const float*)d_in[5];
  const float* b1 = (const float*)d_in[6];
  const float* W2 = (const float*)d_in[7];
  const float* b2 = (const float*)d_in[8];
  const float* g1 = (const float*)d_in[9];
  const float* be1 = (const float*)d_in[10];
  const float* g2 = (const float*)d_in[11];
  const float* be2 = (const float*)d_in[12];

  char* ws = (char*)d_ws;
  const size_t MB = 1024 * 1024;
  float* x1 = (float*)(ws + 0);          // 32MB, becomes x2 in-place after OPROJ
  u16* h = (u16*)(ws + 32 * MB);         // 16MB (reused as h2)
  u16* q = (u16*)(ws + 48 * MB);         // 16MB
  u16* k = (u16*)(ws + 64 * MB);         // 16MB
  u16* vt = (u16*)(ws + 80 * MB);        // 16MB
  u16* o = (u16*)(ws + 96 * MB);         // 16MB
  u16* f = (u16*)(ws + 48 * MB);         // 48MB, aliases q/k/vt (dead after attn)
  u16* wqkv = (u16*)(ws + 112 * MB);     // 6MB
  u16* wo = (u16*)(ws + 118 * MB);       // 2MB
  u16* w1t = (u16*)(ws + 120 * MB);      // 6MB
  u16* w2t = (u16*)(ws + 126 * MB);      // 6MB -> 132MB total
  float* out = (float*)d_out;

  dim3 tb(32, 8);
  tconv<<<dim3(32, 32), tb, 0, stream>>>(Wq, wqkv, 1024, 1024);
  tconv<<<dim3(32, 32), tb, 0, stream>>>(Wk, wqkv + 1024 * 1024, 1024, 1024);
  tconv<<<dim3(32, 32), tb, 0, stream>>>(Wv, wqkv + 2 * 1024 * 1024, 1024, 1024);
  tconv<<<dim3(32, 32), tb, 0, stream>>>(Wo, wo, 1024, 1024);
  tconv<<<dim3(96, 32), tb, 0, stream>>>(W1, w1t, 1024, 3072);
  tconv<<<dim3(32, 96), tb, 0, stream>>>(W2, w2t, 3072, 1024);

  ln_row<true><<<8192, 256, 0, stream>>>(x, g1, be1, x1, h);

  gemm_bt<EPI_QKV><<<dim3(24, 64), 256, 0, stream>>>(h, wqkv, 8192, 3072, 1024,
                                                     nullptr, nullptr, nullptr, nullptr,
                                                     q, k, vt);
  attn_fwd<<<1024, 256, 0, stream>>>(q, k, vt, o);

  gemm_bt<EPI_OPROJ><<<dim3(8, 64), 256, 0, stream>>>(o, wo, 8192, 1024, 1024,
                                                      nullptr, x1, x1, nullptr,
                                                      nullptr, nullptr, nullptr);
  ln_row<false><<<8192, 256, 0, stream>>>(x1, g2, be2, nullptr, h);

  gemm_bt<EPI_FFN1><<<dim3(24, 64), 256, 0, stream>>>(h, w1t, 8192, 3072, 1024,
                                                      b1, nullptr, nullptr, f,
                                                      nullptr, nullptr, nullptr);
  gemm_bt<EPI_FFN2><<<dim3(8, 64), 256, 0, stream>>>(f, w2t, 8192, 1024, 3072,
                                                     b2, x1, out, nullptr,
                                                     nullptr, nullptr, nullptr);
}